// Round 2
// baseline (128.070 us; speedup 1.0000x reference)
//
#include <hip/hip_runtime.h>
#include <stdint.h>

// Problem dims
#define B_DIM 8192
#define I_DIM 512
#define O_DIM 512
#define KDIM  2048   // I_DIM * 4 features: {silu, u0, u1, u2}

// GEMM tile
#define BM 128
#define BN 64
#define BK 32

using bf16x8 = __attribute__((ext_vector_type(8))) short;
using f32x4  = __attribute__((ext_vector_type(4))) float;

__device__ __forceinline__ unsigned short f2bf(float f) {
  union { float f; unsigned int u; } c; c.f = f;
  unsigned int x = c.u;
  unsigned int r = (x + 0x7fffu + ((x >> 16) & 1u)) >> 16;  // RNE
  return (unsigned short)r;
}

// ---------------------------------------------------------------------------
// Kernel 1: A[b][i*4 + {0..3}] = {silu(x), u0, u1, u2}  (bf16)
// u_g = interpolation weight of basis-table row g (G=3 grid, grid_idx = xc+1)
// ---------------------------------------------------------------------------
__global__ __launch_bounds__(256) void build_a(const float* __restrict__ x,
                                               unsigned short* __restrict__ A) {
  const int idx = blockIdx.x * 256 + threadIdx.x;  // one thread per (b, 4-i group)
  const int b = idx >> 7;                          // 128 groups of 4 per row
  const int q = idx & 127;
  const float4 xv = *reinterpret_cast<const float4*>(x + (size_t)b * I_DIM + q * 4);
  union { unsigned short us[16]; uint4 v[2]; } out;
  const float xs[4] = {xv.x, xv.y, xv.z, xv.w};
#pragma unroll
  for (int j = 0; j < 4; ++j) {
    const float xf = xs[j];
    const float s = xf / (1.0f + __expf(-xf));          // silu, f32
    const float xc = fminf(fmaxf(xf, -1.0f), 1.0f);
    const float g = xc + 1.0f;                          // grid_idx in [0,2], exact
    int il = (int)floorf(g);
    if (il > 2) il = 2;
    const float fr = g - (float)il;
    int ih = il + (fr > 0.0f ? 1 : 0);
    if (ih > 2) ih = 2;
    const float u0 = (il == 0 ? 1.0f - fr : 0.0f) + (ih == 0 ? fr : 0.0f);
    const float u1 = (il == 1 ? 1.0f - fr : 0.0f) + (ih == 1 ? fr : 0.0f);
    const float u2 = (il == 2 ? 1.0f - fr : 0.0f) + (ih == 2 ? fr : 0.0f);
    out.us[j * 4 + 0] = f2bf(s);
    out.us[j * 4 + 1] = f2bf(u0);
    out.us[j * 4 + 2] = f2bf(u1);
    out.us[j * 4 + 3] = f2bf(u2);
  }
  uint4* dst = reinterpret_cast<uint4*>(A + (size_t)b * KDIM + q * 16);
  dst[0] = out.v[0];
  dst[1] = out.v[1];
}

// ---------------------------------------------------------------------------
// Kernel 2: Wt[o][i*4 + 0] = imp*bw ; Wt[o][i*4 + 1+g] = (BASIS[g]·cp[i,o,:])*imp*sw
// Stored N-major (Wt[N][K]) so the GEMM reads contiguous k-fragments (NT form).
// BASIS: Gaussian pseudo-B-spline table, knots linspace(-1.3,1.3,9), width .65,
// centers {-.8125,-.4875,-.1625,.1625,.4875}, rows normalized (+1e-6).
// ---------------------------------------------------------------------------
__global__ __launch_bounds__(256) void build_w(const float* __restrict__ cp,
                                               const float* __restrict__ bw,
                                               const float* __restrict__ sw,
                                               const float* __restrict__ imp,
                                               unsigned short* __restrict__ Wt) {
  const int idx = blockIdx.x * 256 + threadIdx.x;  // 512*512 threads
  const int i = idx >> 9;
  const int o = idx & 511;
  const int e = i * O_DIM + o;
  const float im = imp[e];
  const float wb = im * bw[e];
  const float wsp = im * sw[e];
  const float* c = cp + (size_t)e * 5;
  const float c0 = c[0], c1 = c[1], c2 = c[2], c3 = c[3], c4 = c[4];
  const float q0 = (0.54336160f * c0 + 0.31713055f * c1 + 0.11226386f * c2 +
                    0.02410431f * c3 + 0.00313908f * c4) * wsp;
  const float q1 = (0.06493530f * c0 + 0.17651242f * c1 + 0.29101978f * c2 +
                    0.29101978f * c3 + 0.17651242f * c4) * wsp;
  const float q2 = (0.00313908f * c0 + 0.02410431f * c1 + 0.11226386f * c2 +
                    0.31713055f * c3 + 0.54336160f * c4) * wsp;
  ushort4 v;
  v.x = f2bf(wb); v.y = f2bf(q0); v.z = f2bf(q1); v.w = f2bf(q2);
  *reinterpret_cast<ushort4*>(Wt + (size_t)o * KDIM + i * 4) = v;
}

// ---------------------------------------------------------------------------
// Kernel 3: C[M,N] = A[M,K] * Wt[N,K]^T  (bf16 in, f32 out)
// m97-style: 128x64 tile, BK=32, 256 thr (4 waves, 2x2), per-wave 64x32 (4x2
// fragments of 16x16), global_load_lds width-16 staging, 2-barrier K-loop.
// ---------------------------------------------------------------------------
__device__ __forceinline__ void gload16(const void* g, void* lds) {
  __builtin_amdgcn_global_load_lds(
      (const __attribute__((address_space(1))) unsigned int*)g,
      (__attribute__((address_space(3))) unsigned int*)lds,
      16, 0, 0);
}

__global__ __launch_bounds__(256, 2) void gemm(const unsigned short* __restrict__ A,
                                               const unsigned short* __restrict__ Wt,
                                               float* __restrict__ C) {
  __shared__ __align__(16) unsigned short As[BM * BK];  // [128][32] bf16, 8 KB
  __shared__ __align__(16) unsigned short Bs[BN * BK];  // [64][32]  bf16, 4 KB

  const int bid = blockIdx.x;
  const int nt = bid & 7;    // 8 n-tiles
  const int mt = bid >> 3;   // 64 m-tiles
  const int m0 = mt * BM;
  const int n0 = nt * BN;
  const int t = threadIdx.x;
  const int l = t & 63;
  const int w = t >> 6;
  const int wm = w >> 1;     // wave row 0..1 (64 rows each)
  const int wn = w & 1;      // wave col 0..1 (32 cols each)

  f32x4 acc[4][2] = {};

  // Staging: slot s covers 8 elems (16 B); A-tile = 512 slots (2/thread),
  // B-tile = 256 slots (1/thread). LDS dest is linear in lane order (HW rule).
  const int sA1 = t + 256;
  const unsigned short* ga0 = A + (size_t)(m0 + (t   >> 2)) * KDIM + (t   & 3) * 8;
  const unsigned short* ga1 = A + (size_t)(m0 + (sA1 >> 2)) * KDIM + (sA1 & 3) * 8;
  const unsigned short* gb0 = Wt + (size_t)(n0 + (t >> 2)) * KDIM + (t & 3) * 8;
  unsigned short* la0 = &As[t * 8];
  unsigned short* la1 = &As[sA1 * 8];
  unsigned short* lb0 = &Bs[t * 8];

  const int kg = (l >> 4) * 8;  // k-group within fragment
  const int lr = l & 15;        // row/col within 16x16 fragment

  for (int kk = 0; kk < KDIM; kk += BK) {
    gload16(ga0 + kk, la0);
    gload16(ga1 + kk, la1);
    gload16(gb0 + kk, lb0);
    __syncthreads();  // drains vmcnt before barrier (compiler-enforced)

    bf16x8 af[4], bfr[2];
#pragma unroll
    for (int m = 0; m < 4; ++m)
      af[m] = *reinterpret_cast<const bf16x8*>(&As[(wm * 64 + m * 16 + lr) * BK + kg]);
#pragma unroll
    for (int n = 0; n < 2; ++n)
      bfr[n] = *reinterpret_cast<const bf16x8*>(&Bs[(wn * 32 + n * 16 + lr) * BK + kg]);

#pragma unroll
    for (int m = 0; m < 4; ++m)
#pragma unroll
      for (int n = 0; n < 2; ++n)
        acc[m][n] = __builtin_amdgcn_mfma_f32_16x16x32_bf16(af[m], bfr[n], acc[m][n], 0, 0, 0);

    __syncthreads();  // protect LDS before next stage
  }

  // Epilogue: C/D layout col = lane&15, row = (lane>>4)*4 + reg  [m89-verified]
#pragma unroll
  for (int m = 0; m < 4; ++m) {
#pragma unroll
    for (int n = 0; n < 2; ++n) {
      const int col = n0 + wn * 32 + n * 16 + lr;
      const int rbase = m0 + wm * 64 + m * 16 + (l >> 4) * 4;
#pragma unroll
      for (int r = 0; r < 4; ++r)
        C[(size_t)(rbase + r) * O_DIM + col] = acc[m][n][r];
    }
  }
}

// ---------------------------------------------------------------------------
extern "C" void kernel_launch(void* const* d_in, const int* in_sizes, int n_in,
                              void* d_out, int out_size, void* d_ws, size_t ws_size,
                              hipStream_t stream) {
  const float* x   = (const float*)d_in[0];
  const float* cp  = (const float*)d_in[1];
  const float* bw  = (const float*)d_in[2];
  const float* sw  = (const float*)d_in[3];
  const float* imp = (const float*)d_in[4];
  float* out = (float*)d_out;

  unsigned short* Abuf = (unsigned short*)d_ws;                  // [8192][2048] bf16 = 32 MB
  unsigned short* Wbuf = Abuf + (size_t)B_DIM * KDIM;            // [512][2048]  bf16 =  2 MB

  build_a<<<(B_DIM * (I_DIM / 4)) / 256, 256, 0, stream>>>(x, Abuf);
  build_w<<<(I_DIM * O_DIM) / 256, 256, 0, stream>>>(cp, bw, sw, imp, Wbuf);
  gemm<<<(B_DIM / BM) * (O_DIM / BN), 256, 0, stream>>>(Abuf, Wbuf, out);
}

// Round 3
// 121.331 us; speedup vs baseline: 1.0555x; 1.0555x over previous
//
#include <hip/hip_runtime.h>
#include <stdint.h>

// Problem dims
#define B_DIM 8192
#define I_DIM 512
#define O_DIM 512
#define KDIM  2048   // I_DIM * 4 features: {silu, u0, u1, u2}

// GEMM tile
#define BM 128
#define BN 64
#define BK 64        // two 32-wide halves; LDS layout [kh][rows][32]

using bf16x8 = __attribute__((ext_vector_type(8))) short;
using f32x4  = __attribute__((ext_vector_type(4))) float;

__device__ __forceinline__ unsigned short f2bf(float f) {
  union { float f; unsigned int u; } c; c.f = f;
  unsigned int x = c.u;
  unsigned int r = (x + 0x7fffu + ((x >> 16) & 1u)) >> 16;  // RNE
  return (unsigned short)r;
}

// ---------------------------------------------------------------------------
// Kernel 1: A[b][i*4 + {0..3}] = {silu(x), u0, u1, u2}  (bf16)
// ---------------------------------------------------------------------------
__global__ __launch_bounds__(256) void build_a(const float* __restrict__ x,
                                               unsigned short* __restrict__ A) {
  const int idx = blockIdx.x * 256 + threadIdx.x;
  const int b = idx >> 7;
  const int q = idx & 127;
  const float4 xv = *reinterpret_cast<const float4*>(x + (size_t)b * I_DIM + q * 4);
  union { unsigned short us[16]; uint4 v[2]; } out;
  const float xs[4] = {xv.x, xv.y, xv.z, xv.w};
#pragma unroll
  for (int j = 0; j < 4; ++j) {
    const float xf = xs[j];
    const float s = xf / (1.0f + __expf(-xf));
    const float xc = fminf(fmaxf(xf, -1.0f), 1.0f);
    const float g = xc + 1.0f;                          // grid_idx in [0,2]
    int il = (int)floorf(g);
    if (il > 2) il = 2;
    const float fr = g - (float)il;
    int ih = il + (fr > 0.0f ? 1 : 0);
    if (ih > 2) ih = 2;
    const float u0 = (il == 0 ? 1.0f - fr : 0.0f) + (ih == 0 ? fr : 0.0f);
    const float u1 = (il == 1 ? 1.0f - fr : 0.0f) + (ih == 1 ? fr : 0.0f);
    const float u2 = (il == 2 ? 1.0f - fr : 0.0f) + (ih == 2 ? fr : 0.0f);
    out.us[j * 4 + 0] = f2bf(s);
    out.us[j * 4 + 1] = f2bf(u0);
    out.us[j * 4 + 2] = f2bf(u1);
    out.us[j * 4 + 3] = f2bf(u2);
  }
  uint4* dst = reinterpret_cast<uint4*>(A + (size_t)b * KDIM + q * 16);
  dst[0] = out.v[0];
  dst[1] = out.v[1];
}

// ---------------------------------------------------------------------------
// Kernel 2: Wt[o][i*4+0]=imp*bw ; Wt[o][i*4+1+g]=(BASIS[g]·cp)*imp*sw  (N-major)
// ---------------------------------------------------------------------------
__global__ __launch_bounds__(256) void build_w(const float* __restrict__ cp,
                                               const float* __restrict__ bw,
                                               const float* __restrict__ sw,
                                               const float* __restrict__ imp,
                                               unsigned short* __restrict__ Wt) {
  const int idx = blockIdx.x * 256 + threadIdx.x;
  const int i = idx >> 9;
  const int o = idx & 511;
  const int e = i * O_DIM + o;
  const float im = imp[e];
  const float wb = im * bw[e];
  const float wsp = im * sw[e];
  const float* c = cp + (size_t)e * 5;
  const float c0 = c[0], c1 = c[1], c2 = c[2], c3 = c[3], c4 = c[4];
  const float q0 = (0.54336160f * c0 + 0.31713055f * c1 + 0.11226386f * c2 +
                    0.02410431f * c3 + 0.00313908f * c4) * wsp;
  const float q1 = (0.06493530f * c0 + 0.17651242f * c1 + 0.29101978f * c2 +
                    0.29101978f * c3 + 0.17651242f * c4) * wsp;
  const float q2 = (0.00313908f * c0 + 0.02410431f * c1 + 0.11226386f * c2 +
                    0.31713055f * c3 + 0.54336160f * c4) * wsp;
  ushort4 v;
  v.x = f2bf(wb); v.y = f2bf(q0); v.z = f2bf(q1); v.w = f2bf(q2);
  *reinterpret_cast<ushort4*>(Wt + (size_t)o * KDIM + i * 4) = v;
}

// ---------------------------------------------------------------------------
// Kernel 3: C = A[M,K] * Wt[N,K]^T, bf16 MFMA, double-buffered LDS, BK=64.
// 256 thr (4 waves 2x2); wave owns 64x32 (4x2 frags). T1 XCD swizzle.
// ---------------------------------------------------------------------------
__device__ __forceinline__ void gload16(const void* g, void* lds) {
  __builtin_amdgcn_global_load_lds(
      (const __attribute__((address_space(1))) unsigned int*)g,
      (__attribute__((address_space(3))) unsigned int*)lds,
      16, 0, 0);
}

__global__ __launch_bounds__(256, 2) void gemm(const unsigned short* __restrict__ A,
                                               const unsigned short* __restrict__ Wt,
                                               float* __restrict__ C) {
  // [buf][kh][rows][32] elems: A 2*2*128*32, B 2*2*64*32  -> 48 KB total
  __shared__ __align__(16) unsigned short As[2 * 8192];
  __shared__ __align__(16) unsigned short Bs[2 * 4096];

  // T1: XCD-aware swizzle (8 XCDs, 512 blocks, bijective since 512%8==0).
  // orig bid round-robins XCDs; remap so XCD x owns contiguous mt chunk with
  // all 8 nt time-adjacent -> A-panel L2-resident per XCD.
  const int bid = blockIdx.x;
  const int nb = (bid & 7) * 64 + (bid >> 3);
  const int mt = nb >> 3;
  const int nt = nb & 7;
  const int m0 = mt * BM;
  const int n0 = nt * BN;

  const int t = threadIdx.x;
  const int l = t & 63;
  const int w = t >> 6;
  const int wm = w >> 1;     // 2 m-halves of 64 rows
  const int wn = w & 1;      // 2 n-halves of 32 cols
  const int lr = l & 15;
  const int kg = (l >> 4) * 8;

  f32x4 acc[4][2] = {};

  // Staging slot maps (LDS written linearly in slot order; per-lane GLOBAL
  // address chosen to realize [kh][row][32] layout — m173 pattern).
  // A: 1024 slots: s = kh*512 + row*4 + c  (row<128, c<4, elem col = kh*32+c*8)
  // B:  512 slots: s = kh*256 + row*4 + c  (row<64)
  const unsigned short* gA[4];
  unsigned short* lA[2][4];
  const unsigned short* gB[2];
  unsigned short* lB[2][2];
#pragma unroll
  for (int i = 0; i < 4; ++i) {
    const int s = t + 256 * i;
    const int kh = s >> 9, row = (s >> 2) & 127, c = s & 3;
    gA[i] = A + (size_t)(m0 + row) * KDIM + kh * 32 + c * 8;
    lA[0][i] = As + s * 8;
    lA[1][i] = As + 8192 + s * 8;
  }
#pragma unroll
  for (int i = 0; i < 2; ++i) {
    const int s = t + 256 * i;
    const int kh = s >> 8, row = (s >> 2) & 63, c = s & 3;
    gB[i] = Wt + (size_t)(n0 + row) * KDIM + kh * 32 + c * 8;
    lB[0][i] = Bs + s * 8;
    lB[1][i] = Bs + 4096 + s * 8;
  }

  const int aoff = (wm * 64 + lr) * 32 + kg;   // + m*512 + kh*4096
  const int boff = (wn * 32 + lr) * 32 + kg;   // + n*512 + kh*2048

#define STAGE(buf, tile) do {                                                  \
    const int ko = (tile) * BK;                                                \
    _Pragma("unroll") for (int i = 0; i < 4; ++i) gload16(gA[i] + ko, lA[buf][i]); \
    _Pragma("unroll") for (int i = 0; i < 2; ++i) gload16(gB[i] + ko, lB[buf][i]); \
  } while (0)

#define COMPUTE(buf) do {                                                      \
    const unsigned short* Ab = As + (buf) * 8192;                              \
    const unsigned short* Bb = Bs + (buf) * 4096;                              \
    bf16x8 af[2][4], bfr[2][2];                                                \
    _Pragma("unroll") for (int h = 0; h < 2; ++h)                              \
      _Pragma("unroll") for (int m = 0; m < 4; ++m)                            \
        af[h][m] = *reinterpret_cast<const bf16x8*>(Ab + h * 4096 + aoff + m * 512); \
    _Pragma("unroll") for (int h = 0; h < 2; ++h)                              \
      _Pragma("unroll") for (int n = 0; n < 2; ++n)                            \
        bfr[h][n] = *reinterpret_cast<const bf16x8*>(Bb + h * 2048 + boff + n * 512); \
    _Pragma("unroll") for (int h = 0; h < 2; ++h)                              \
      _Pragma("unroll") for (int m = 0; m < 4; ++m)                            \
        _Pragma("unroll") for (int n = 0; n < 2; ++n)                          \
          acc[m][n] = __builtin_amdgcn_mfma_f32_16x16x32_bf16(af[h][m], bfr[h][n], acc[m][n], 0, 0, 0); \
  } while (0)

  // 32 K-tiles, double-buffered. __syncthreads drains vmcnt+lgkmcnt (m97 asm),
  // so each tile's loads fly during the OTHER buffer's ds_read+MFMA.
  STAGE(0, 0);
  __syncthreads();
#pragma unroll 1
  for (int tl = 0; tl < 30; tl += 2) {
    STAGE(1, tl + 1);
    COMPUTE(0);
    __syncthreads();
    STAGE(0, tl + 2);
    COMPUTE(1);
    __syncthreads();
  }
  STAGE(1, 31);
  COMPUTE(0);
  __syncthreads();
  COMPUTE(1);

#undef STAGE
#undef COMPUTE

  // Epilogue: C/D layout col = lane&15, row = (lane>>4)*4 + reg [m89]
#pragma unroll
  for (int m = 0; m < 4; ++m) {
#pragma unroll
    for (int n = 0; n < 2; ++n) {
      const int col = n0 + wn * 32 + n * 16 + lr;
      const int rbase = m0 + wm * 64 + m * 16 + (l >> 4) * 4;
#pragma unroll
      for (int r = 0; r < 4; ++r)
        C[(size_t)(rbase + r) * O_DIM + col] = acc[m][n][r];
    }
  }
}

// ---------------------------------------------------------------------------
extern "C" void kernel_launch(void* const* d_in, const int* in_sizes, int n_in,
                              void* d_out, int out_size, void* d_ws, size_t ws_size,
                              hipStream_t stream) {
  const float* x   = (const float*)d_in[0];
  const float* cp  = (const float*)d_in[1];
  const float* bw  = (const float*)d_in[2];
  const float* sw  = (const float*)d_in[3];
  const float* imp = (const float*)d_in[4];
  float* out = (float*)d_out;

  unsigned short* Abuf = (unsigned short*)d_ws;                  // 32 MB bf16
  unsigned short* Wbuf = Abuf + (size_t)B_DIM * KDIM;            //  2 MB bf16

  build_a<<<(B_DIM * (I_DIM / 4)) / 256, 256, 0, stream>>>(x, Abuf);
  build_w<<<(I_DIM * O_DIM) / 256, 256, 0, stream>>>(cp, bw, sw, imp, Wbuf);
  gemm<<<(B_DIM / BM) * (O_DIM / BN), 256, 0, stream>>>(Abuf, Wbuf, out);
}

// Round 4
// 118.712 us; speedup vs baseline: 1.0788x; 1.0221x over previous
//
#include <hip/hip_runtime.h>
#include <stdint.h>

// Problem dims
#define B_DIM 8192
#define I_DIM 512
#define O_DIM 512
#define KDIM  2048   // I_DIM * 4 features: {silu, u0, u1, u2}

// GEMM tile
#define BM 128
#define BN 64
#define BK 64        // two 32-wide halves; LDS layout [kh][rows][32]

using bf16x8 = __attribute__((ext_vector_type(8))) short;
using f32x4  = __attribute__((ext_vector_type(4))) float;

__device__ __forceinline__ unsigned short f2bf(float f) {
  union { float f; unsigned int u; } c; c.f = f;
  unsigned int x = c.u;
  unsigned int r = (x + 0x7fffu + ((x >> 16) & 1u)) >> 16;  // RNE
  return (unsigned short)r;
}

// ---------------------------------------------------------------------------
// Fused prologue. Blocks [0, 4096): A[b][i*4+{0..3}] = {silu(x), u0, u1, u2}.
// Blocks [4096, 5120): Wt[o][i*4+0]=imp*bw ; Wt[o][i*4+1+g]=(BASIS[g]·cp)*imp*sw
// (N-major so the GEMM reads contiguous k-fragments).
// BASIS: Gaussian pseudo-B-spline, knots linspace(-1.3,1.3,9), width .65,
// centers {-.8125,-.4875,-.1625,.1625,.4875}, rows normalized (+1e-6).
// ---------------------------------------------------------------------------
__global__ __launch_bounds__(256) void build_aw(const float* __restrict__ x,
                                                const float* __restrict__ cp,
                                                const float* __restrict__ bw,
                                                const float* __restrict__ sw,
                                                const float* __restrict__ imp,
                                                unsigned short* __restrict__ A,
                                                unsigned short* __restrict__ Wt) {
  if (blockIdx.x < 4096) {
    const int idx = blockIdx.x * 256 + threadIdx.x;  // one thread per (b, 4-i group)
    const int b = idx >> 7;
    const int q = idx & 127;
    const float4 xv = *reinterpret_cast<const float4*>(x + (size_t)b * I_DIM + q * 4);
    union { unsigned short us[16]; uint4 v[2]; } out;
    const float xs[4] = {xv.x, xv.y, xv.z, xv.w};
#pragma unroll
    for (int j = 0; j < 4; ++j) {
      const float xf = xs[j];
      const float s = xf / (1.0f + __expf(-xf));          // silu, f32
      const float xc = fminf(fmaxf(xf, -1.0f), 1.0f);
      const float g = xc + 1.0f;                          // grid_idx in [0,2]
      int il = (int)floorf(g);
      if (il > 2) il = 2;
      const float fr = g - (float)il;
      int ih = il + (fr > 0.0f ? 1 : 0);
      if (ih > 2) ih = 2;
      const float u0 = (il == 0 ? 1.0f - fr : 0.0f) + (ih == 0 ? fr : 0.0f);
      const float u1 = (il == 1 ? 1.0f - fr : 0.0f) + (ih == 1 ? fr : 0.0f);
      const float u2 = (il == 2 ? 1.0f - fr : 0.0f) + (ih == 2 ? fr : 0.0f);
      out.us[j * 4 + 0] = f2bf(s);
      out.us[j * 4 + 1] = f2bf(u0);
      out.us[j * 4 + 2] = f2bf(u1);
      out.us[j * 4 + 3] = f2bf(u2);
    }
    uint4* dst = reinterpret_cast<uint4*>(A + (size_t)b * KDIM + q * 16);
    dst[0] = out.v[0];
    dst[1] = out.v[1];
  } else {
    const int idx = (blockIdx.x - 4096) * 256 + threadIdx.x;  // 512*512 threads
    const int i = idx >> 9;
    const int o = idx & 511;
    const int e = i * O_DIM + o;
    const float im = imp[e];
    const float wb = im * bw[e];
    const float wsp = im * sw[e];
    const float* c = cp + (size_t)e * 5;
    const float c0 = c[0], c1 = c[1], c2 = c[2], c3 = c[3], c4 = c[4];
    const float q0 = (0.54336160f * c0 + 0.31713055f * c1 + 0.11226386f * c2 +
                      0.02410431f * c3 + 0.00313908f * c4) * wsp;
    const float q1 = (0.06493530f * c0 + 0.17651242f * c1 + 0.29101978f * c2 +
                      0.29101978f * c3 + 0.17651242f * c4) * wsp;
    const float q2 = (0.00313908f * c0 + 0.02410431f * c1 + 0.11226386f * c2 +
                      0.31713055f * c3 + 0.54336160f * c4) * wsp;
    ushort4 v;
    v.x = f2bf(wb); v.y = f2bf(q0); v.z = f2bf(q1); v.w = f2bf(q2);
    *reinterpret_cast<ushort4*>(Wt + (size_t)o * KDIM + i * 4) = v;
  }
}

// ---------------------------------------------------------------------------
// GEMM: C = A[M,K] * Wt[N,K]^T, bf16 MFMA, double-buffered LDS, BK=64.
// 256 thr (4 waves 2x2); wave owns 64x32 (4x2 frags). T1 XCD swizzle.
// launch_bounds(256,3): LDS 48KB -> 3 blocks/CU (144<=160KB), VGPR 40 << cap.
// ---------------------------------------------------------------------------
__device__ __forceinline__ void gload16(const void* g, void* lds) {
  __builtin_amdgcn_global_load_lds(
      (const __attribute__((address_space(1))) unsigned int*)g,
      (__attribute__((address_space(3))) unsigned int*)lds,
      16, 0, 0);
}

__global__ __launch_bounds__(256, 3) void gemm(const unsigned short* __restrict__ A,
                                               const unsigned short* __restrict__ Wt,
                                               float* __restrict__ C) {
  // [buf][kh][rows][32] elems: A 2*2*128*32, B 2*2*64*32  -> 48 KB total
  __shared__ __align__(16) unsigned short As[2 * 8192];
  __shared__ __align__(16) unsigned short Bs[2 * 4096];

  // T1: XCD-aware swizzle (8 XCDs, 512 blocks, bijective since 512%8==0).
  const int bid = blockIdx.x;
  const int nb = (bid & 7) * 64 + (bid >> 3);
  const int mt = nb >> 3;
  const int nt = nb & 7;
  const int m0 = mt * BM;
  const int n0 = nt * BN;

  const int t = threadIdx.x;
  const int l = t & 63;
  const int w = t >> 6;
  const int wm = w >> 1;     // 2 m-halves of 64 rows
  const int wn = w & 1;      // 2 n-halves of 32 cols
  const int lr = l & 15;
  const int kg = (l >> 4) * 8;

  f32x4 acc[4][2] = {};

  // Staging slot maps (LDS written linearly in slot order; per-lane GLOBAL
  // address chosen to realize [kh][row][32] layout — m173 pattern).
  const unsigned short* gA[4];
  unsigned short* lA[2][4];
  const unsigned short* gB[2];
  unsigned short* lB[2][2];
#pragma unroll
  for (int i = 0; i < 4; ++i) {
    const int s = t + 256 * i;
    const int kh = s >> 9, row = (s >> 2) & 127, c = s & 3;
    gA[i] = A + (size_t)(m0 + row) * KDIM + kh * 32 + c * 8;
    lA[0][i] = As + s * 8;
    lA[1][i] = As + 8192 + s * 8;
  }
#pragma unroll
  for (int i = 0; i < 2; ++i) {
    const int s = t + 256 * i;
    const int kh = s >> 8, row = (s >> 2) & 63, c = s & 3;
    gB[i] = Wt + (size_t)(n0 + row) * KDIM + kh * 32 + c * 8;
    lB[0][i] = Bs + s * 8;
    lB[1][i] = Bs + 4096 + s * 8;
  }

  const int aoff = (wm * 64 + lr) * 32 + kg;   // + m*512 + kh*4096
  const int boff = (wn * 32 + lr) * 32 + kg;   // + n*512 + kh*2048

#define STAGE(buf, tile) do {                                                  \
    const int ko = (tile) * BK;                                                \
    _Pragma("unroll") for (int i = 0; i < 4; ++i) gload16(gA[i] + ko, lA[buf][i]); \
    _Pragma("unroll") for (int i = 0; i < 2; ++i) gload16(gB[i] + ko, lB[buf][i]); \
  } while (0)

#define COMPUTE(buf) do {                                                      \
    const unsigned short* Ab = As + (buf) * 8192;                              \
    const unsigned short* Bb = Bs + (buf) * 4096;                              \
    bf16x8 af[2][4], bfr[2][2];                                                \
    _Pragma("unroll") for (int h = 0; h < 2; ++h)                              \
      _Pragma("unroll") for (int m = 0; m < 4; ++m)                            \
        af[h][m] = *reinterpret_cast<const bf16x8*>(Ab + h * 4096 + aoff + m * 512); \
    _Pragma("unroll") for (int h = 0; h < 2; ++h)                              \
      _Pragma("unroll") for (int n = 0; n < 2; ++n)                            \
        bfr[h][n] = *reinterpret_cast<const bf16x8*>(Bb + h * 2048 + boff + n * 512); \
    _Pragma("unroll") for (int h = 0; h < 2; ++h)                              \
      _Pragma("unroll") for (int m = 0; m < 4; ++m)                            \
        _Pragma("unroll") for (int n = 0; n < 2; ++n)                          \
          acc[m][n] = __builtin_amdgcn_mfma_f32_16x16x32_bf16(af[h][m], bfr[h][n], acc[m][n], 0, 0, 0); \
  } while (0)

  // 32 K-tiles, double-buffered. __syncthreads drains vmcnt+lgkmcnt (m97 asm),
  // so each tile's loads fly during the OTHER buffer's ds_read+MFMA.
  STAGE(0, 0);
  __syncthreads();
#pragma unroll 1
  for (int tl = 0; tl < 30; tl += 2) {
    STAGE(1, tl + 1);
    COMPUTE(0);
    __syncthreads();
    STAGE(0, tl + 2);
    COMPUTE(1);
    __syncthreads();
  }
  STAGE(1, 31);
  COMPUTE(0);
  __syncthreads();
  COMPUTE(1);

#undef STAGE
#undef COMPUTE

  // Epilogue: C/D layout col = lane&15, row = (lane>>4)*4 + reg [m89]
#pragma unroll
  for (int m = 0; m < 4; ++m) {
#pragma unroll
    for (int n = 0; n < 2; ++n) {
      const int col = n0 + wn * 32 + n * 16 + lr;
      const int rbase = m0 + wm * 64 + m * 16 + (l >> 4) * 4;
#pragma unroll
      for (int r = 0; r < 4; ++r)
        C[(size_t)(rbase + r) * O_DIM + col] = acc[m][n][r];
    }
  }
}

// ---------------------------------------------------------------------------
extern "C" void kernel_launch(void* const* d_in, const int* in_sizes, int n_in,
                              void* d_out, int out_size, void* d_ws, size_t ws_size,
                              hipStream_t stream) {
  const float* x   = (const float*)d_in[0];
  const float* cp  = (const float*)d_in[1];
  const float* bw  = (const float*)d_in[2];
  const float* sw  = (const float*)d_in[3];
  const float* imp = (const float*)d_in[4];
  float* out = (float*)d_out;

  unsigned short* Abuf = (unsigned short*)d_ws;                  // 32 MB bf16
  unsigned short* Wbuf = Abuf + (size_t)B_DIM * KDIM;            //  2 MB bf16

  build_aw<<<4096 + 1024, 256, 0, stream>>>(x, cp, bw, sw, imp, Abuf, Wbuf);
  gemm<<<(B_DIM / BM) * (O_DIM / BN), 256, 0, stream>>>(Abuf, Wbuf, out);
}

// Round 5
// 108.110 us; speedup vs baseline: 1.1846x; 1.0981x over previous
//
#include <hip/hip_runtime.h>
#include <stdint.h>

// Problem dims
#define B_DIM 8192
#define I_DIM 512
#define O_DIM 512
#define KDIM  2048   // I_DIM * 4 features: {silu, u0, u1, u2}

// GEMM tile
#define BM 128
#define BN 64
#define BK 64        // two 32-wide halves; LDS layout [kh][rows][32]

using bf16x8 = __attribute__((ext_vector_type(8))) short;
using f32x4  = __attribute__((ext_vector_type(4))) float;

__device__ __forceinline__ unsigned short f2bf(float f) {
  union { float f; unsigned int u; } c; c.f = f;
  unsigned int x = c.u;
  unsigned int r = (x + 0x7fffu + ((x >> 16) & 1u)) >> 16;  // RNE
  return (unsigned short)r;
}

// ---------------------------------------------------------------------------
// Fused prologue. Blocks [0, 4096): A[b][i*4+{0..3}] = {silu(x), u0, u1, u2}.
// Blocks [4096, 5120): Wt[o][i*4+0]=imp*bw ; Wt[o][i*4+1+g]=(BASIS[g]·cp)*imp*sw
// ---------------------------------------------------------------------------
__global__ __launch_bounds__(256) void build_aw(const float* __restrict__ x,
                                                const float* __restrict__ cp,
                                                const float* __restrict__ bw,
                                                const float* __restrict__ sw,
                                                const float* __restrict__ imp,
                                                unsigned short* __restrict__ A,
                                                unsigned short* __restrict__ Wt) {
  if (blockIdx.x < 4096) {
    const int idx = blockIdx.x * 256 + threadIdx.x;
    const int b = idx >> 7;
    const int q = idx & 127;
    const float4 xv = *reinterpret_cast<const float4*>(x + (size_t)b * I_DIM + q * 4);
    union { unsigned short us[16]; uint4 v[2]; } out;
    const float xs[4] = {xv.x, xv.y, xv.z, xv.w};
#pragma unroll
    for (int j = 0; j < 4; ++j) {
      const float xf = xs[j];
      const float s = xf / (1.0f + __expf(-xf));          // silu, f32
      const float xc = fminf(fmaxf(xf, -1.0f), 1.0f);
      const float g = xc + 1.0f;                          // grid_idx in [0,2]
      int il = (int)floorf(g);
      if (il > 2) il = 2;
      const float fr = g - (float)il;
      int ih = il + (fr > 0.0f ? 1 : 0);
      if (ih > 2) ih = 2;
      const float u0 = (il == 0 ? 1.0f - fr : 0.0f) + (ih == 0 ? fr : 0.0f);
      const float u1 = (il == 1 ? 1.0f - fr : 0.0f) + (ih == 1 ? fr : 0.0f);
      const float u2 = (il == 2 ? 1.0f - fr : 0.0f) + (ih == 2 ? fr : 0.0f);
      out.us[j * 4 + 0] = f2bf(s);
      out.us[j * 4 + 1] = f2bf(u0);
      out.us[j * 4 + 2] = f2bf(u1);
      out.us[j * 4 + 3] = f2bf(u2);
    }
    uint4* dst = reinterpret_cast<uint4*>(A + (size_t)b * KDIM + q * 16);
    dst[0] = out.v[0];
    dst[1] = out.v[1];
  } else {
    const int idx = (blockIdx.x - 4096) * 256 + threadIdx.x;
    const int i = idx >> 9;
    const int o = idx & 511;
    const int e = i * O_DIM + o;
    const float im = imp[e];
    const float wb = im * bw[e];
    const float wsp = im * sw[e];
    const float* c = cp + (size_t)e * 5;
    const float c0 = c[0], c1 = c[1], c2 = c[2], c3 = c[3], c4 = c[4];
    const float q0 = (0.54336160f * c0 + 0.31713055f * c1 + 0.11226386f * c2 +
                      0.02410431f * c3 + 0.00313908f * c4) * wsp;
    const float q1 = (0.06493530f * c0 + 0.17651242f * c1 + 0.29101978f * c2 +
                      0.29101978f * c3 + 0.17651242f * c4) * wsp;
    const float q2 = (0.00313908f * c0 + 0.02410431f * c1 + 0.11226386f * c2 +
                      0.31713055f * c3 + 0.54336160f * c4) * wsp;
    ushort4 v;
    v.x = f2bf(wb); v.y = f2bf(q0); v.z = f2bf(q1); v.w = f2bf(q2);
    *reinterpret_cast<ushort4*>(Wt + (size_t)o * KDIM + i * 4) = v;
  }
}

// ---------------------------------------------------------------------------
// GEMM: C = A[M,K] * Wt[N,K]^T, bf16 MFMA, BK=64, 4 waves (2x2), T1 swizzle.
// Sync structure (T3/T4): 2-tile-deep prefetch, counted s_waitcnt vmcnt(6)
// (= 6 gload_lds of the NEXT tile stay in flight across barriers), raw
// s_barrier. Never drains vmcnt to 0 in the main loop (m218 mechanism).
//   iter: wait vmcnt(6); bar; COMPUTE(cur); bar; STAGE(cur, t+2)
// barrier #1: all waves' cur-tile loads landed (each waited its own 6).
// barrier #2: all waves done READING buf[cur] before it is re-staged.
// ---------------------------------------------------------------------------
__device__ __forceinline__ void gload16(const void* g, void* lds) {
  __builtin_amdgcn_global_load_lds(
      (const __attribute__((address_space(1))) unsigned int*)g,
      (__attribute__((address_space(3))) unsigned int*)lds,
      16, 0, 0);
}

#define WAITV(n) asm volatile("s_waitcnt vmcnt(" #n ")" ::: "memory")

__global__ __launch_bounds__(256, 3) void gemm(const unsigned short* __restrict__ A,
                                               const unsigned short* __restrict__ Wt,
                                               float* __restrict__ C) {
  // [buf][kh][rows][32] elems: A 2*2*128*32, B 2*2*64*32  -> 48 KB total
  __shared__ __align__(16) unsigned short As[2 * 8192];
  __shared__ __align__(16) unsigned short Bs[2 * 4096];

  // T1: XCD-aware swizzle (8 XCDs, 512 blocks, bijective since 512%8==0).
  const int bid = blockIdx.x;
  const int nb = (bid & 7) * 64 + (bid >> 3);
  const int mt = nb >> 3;
  const int nt = nb & 7;
  const int m0 = mt * BM;
  const int n0 = nt * BN;

  const int t = threadIdx.x;
  const int l = t & 63;
  const int w = t >> 6;
  const int wm = w >> 1;     // 2 m-halves of 64 rows
  const int wn = w & 1;      // 2 n-halves of 32 cols
  const int lr = l & 15;
  const int kg = (l >> 4) * 8;

  f32x4 acc[4][2] = {};

  // Staging slot maps (LDS written linearly in slot order; per-lane GLOBAL
  // address realizes [kh][row][32] layout — m173 pattern).
  const unsigned short* gA[4];
  unsigned short* lA[2][4];
  const unsigned short* gB[2];
  unsigned short* lB[2][2];
#pragma unroll
  for (int i = 0; i < 4; ++i) {
    const int s = t + 256 * i;
    const int kh = s >> 9, row = (s >> 2) & 127, c = s & 3;
    gA[i] = A + (size_t)(m0 + row) * KDIM + kh * 32 + c * 8;
    lA[0][i] = As + s * 8;
    lA[1][i] = As + 8192 + s * 8;
  }
#pragma unroll
  for (int i = 0; i < 2; ++i) {
    const int s = t + 256 * i;
    const int kh = s >> 8, row = (s >> 2) & 63, c = s & 3;
    gB[i] = Wt + (size_t)(n0 + row) * KDIM + kh * 32 + c * 8;
    lB[0][i] = Bs + s * 8;
    lB[1][i] = Bs + 4096 + s * 8;
  }

  const int aoff = (wm * 64 + lr) * 32 + kg;   // + m*512 + kh*4096
  const int boff = (wn * 32 + lr) * 32 + kg;   // + n*512 + kh*2048

#define STAGE(buf, tile) do {                                                  \
    const int ko = (tile) * BK;                                                \
    _Pragma("unroll") for (int i = 0; i < 4; ++i) gload16(gA[i] + ko, lA[buf][i]); \
    _Pragma("unroll") for (int i = 0; i < 2; ++i) gload16(gB[i] + ko, lB[buf][i]); \
  } while (0)

#define COMPUTE(buf) do {                                                      \
    const unsigned short* Ab = As + (buf) * 8192;                              \
    const unsigned short* Bb = Bs + (buf) * 4096;                              \
    bf16x8 af[2][4], bfr[2][2];                                                \
    _Pragma("unroll") for (int h = 0; h < 2; ++h)                              \
      _Pragma("unroll") for (int m = 0; m < 4; ++m)                            \
        af[h][m] = *reinterpret_cast<const bf16x8*>(Ab + h * 4096 + aoff + m * 512); \
    _Pragma("unroll") for (int h = 0; h < 2; ++h)                              \
      _Pragma("unroll") for (int n = 0; n < 2; ++n)                            \
        bfr[h][n] = *reinterpret_cast<const bf16x8*>(Bb + h * 2048 + boff + n * 512); \
    _Pragma("unroll") for (int h = 0; h < 2; ++h)                              \
      _Pragma("unroll") for (int m = 0; m < 4; ++m)                            \
        _Pragma("unroll") for (int n = 0; n < 2; ++n)                          \
          acc[m][n] = __builtin_amdgcn_mfma_f32_16x16x32_bf16(af[h][m], bfr[h][n], acc[m][n], 0, 0, 0); \
  } while (0)

  // 32 K-tiles, 2 tiles in flight. Static buf indices everywhere (rule #20).
  STAGE(0, 0);
  STAGE(1, 1);
#pragma unroll 1
  for (int tl = 0; tl < 28; tl += 2) {
    WAITV(6); __builtin_amdgcn_s_barrier();
    COMPUTE(0);
    __builtin_amdgcn_s_barrier();
    STAGE(0, tl + 2);
    WAITV(6); __builtin_amdgcn_s_barrier();
    COMPUTE(1);
    __builtin_amdgcn_s_barrier();
    STAGE(1, tl + 3);
  }
  // tiles 28..31 (stages 30,31 issued here; never vmcnt(0) until the end)
  WAITV(6); __builtin_amdgcn_s_barrier();
  COMPUTE(0);
  __builtin_amdgcn_s_barrier();
  STAGE(0, 30);
  WAITV(6); __builtin_amdgcn_s_barrier();
  COMPUTE(1);
  __builtin_amdgcn_s_barrier();
  STAGE(1, 31);
  WAITV(6); __builtin_amdgcn_s_barrier();
  COMPUTE(0);
  WAITV(0); __builtin_amdgcn_s_barrier();
  COMPUTE(1);

#undef STAGE
#undef COMPUTE

  // Epilogue: C/D layout col = lane&15, row = (lane>>4)*4 + reg [m89]
#pragma unroll
  for (int m = 0; m < 4; ++m) {
#pragma unroll
    for (int n = 0; n < 2; ++n) {
      const int col = n0 + wn * 32 + n * 16 + lr;
      const int rbase = m0 + wm * 64 + m * 16 + (l >> 4) * 4;
#pragma unroll
      for (int r = 0; r < 4; ++r)
        C[(size_t)(rbase + r) * O_DIM + col] = acc[m][n][r];
    }
  }
}

// ---------------------------------------------------------------------------
extern "C" void kernel_launch(void* const* d_in, const int* in_sizes, int n_in,
                              void* d_out, int out_size, void* d_ws, size_t ws_size,
                              hipStream_t stream) {
  const float* x   = (const float*)d_in[0];
  const float* cp  = (const float*)d_in[1];
  const float* bw  = (const float*)d_in[2];
  const float* sw  = (const float*)d_in[3];
  const float* imp = (const float*)d_in[4];
  float* out = (float*)d_out;

  unsigned short* Abuf = (unsigned short*)d_ws;                  // 32 MB bf16
  unsigned short* Wbuf = Abuf + (size_t)B_DIM * KDIM;            //  2 MB bf16

  build_aw<<<4096 + 1024, 256, 0, stream>>>(x, cp, bw, sw, imp, Abuf, Wbuf);
  gemm<<<(B_DIM / BM) * (O_DIM / BN), 256, 0, stream>>>(Abuf, Wbuf, out);
}